// Round 1
// baseline (3902.615 us; speedup 1.0000x reference)
//
#include <hip/hip_runtime.h>
#include <math.h>

#define NHID 512
#define KTOT 1536   // 1024 (gru_in) + 512 (h gathered)

__device__ __forceinline__ float sigf(float x) { return 1.0f / (1.0f + expf(-x)); }

// ---------------------------------------------------------------------------
// prep: per-(obs, d) features, loss partial, gru_in -> A[:, 0:1024]
// ---------------------------------------------------------------------------
__global__ void prep_kernel(const float* __restrict__ p,
                            const float* __restrict__ X,
                            const float* __restrict__ Mm,
                            const int* __restrict__ iobs,
                            const float* __restrict__ wprep,
                            const float* __restrict__ bprep,
                            float* __restrict__ A,
                            float* __restrict__ loss_out,
                            int nobs)
{
  __shared__ float sw[4096];   // w_prep [64][4][16]
  __shared__ float sb[1024];   // bias_prep [64][16]
  for (int t = threadIdx.x; t < 4096; t += 256) sw[t] = wprep[t];
  for (int t = threadIdx.x; t < 1024; t += 256) sb[t] = bprep[t];
  __syncthreads();

  int gt = blockIdx.x * 256 + threadIdx.x;
  int j = gt >> 6;     // obs row
  int d = gt & 63;     // feature dim
  float lossp = 0.0f;
  if (j < nobs) {
    int i = iobs[j];
    float mean = p[(size_t)i * 128 + d];
    float var  = fabsf(p[(size_t)i * 128 + 64 + d]) + 1e-6f;
    float x = X[(size_t)j * 64 + d];
    float m = Mm[(size_t)j * 64 + d];
    float err = (x - mean) / sqrtf(var);
    lossp = 0.5f * (err * err + logf(var)) * m;

    float* Ar = A + (size_t)j * KTOT + d * 16;
    const float* w = sw + d * 64;   // [4][16]: f0=X f1=mean f2=var f3=err
    const float* b = sb + d * 16;
    #pragma unroll
    for (int ph = 0; ph < 16; ++ph) {
      float v = x * w[ph] + mean * w[16 + ph] + var * w[32 + ph] + err * w[48 + ph] + b[ph];
      Ar[ph] = fmaxf(v, 0.0f) * m;
    }
  }
  // wave (64-lane) reduction of loss, one atomic per wave
  #pragma unroll
  for (int off = 32; off > 0; off >>= 1) lossp += __shfl_down(lossp, off, 64);
  if ((threadIdx.x & 63) == 0) atomicAdd(loss_out, lossp);
}

// ---------------------------------------------------------------------------
// gather: h[i_obs] -> A[:, 1024:1536]
// ---------------------------------------------------------------------------
__global__ void gather_kernel(const float* __restrict__ h,
                              const int* __restrict__ iobs,
                              float* __restrict__ A, int nobs)
{
  int gt = blockIdx.x * 256 + threadIdx.x;   // nobs*128 threads, float4 each
  int j = gt >> 7;
  int c4 = gt & 127;
  if (j >= nobs) return;
  int i = iobs[j];
  float4 v = *(const float4*)(h + (size_t)i * NHID + c4 * 4);
  *(float4*)(A + (size_t)j * KTOT + 1024 + c4 * 4) = v;
}

// ---------------------------------------------------------------------------
// fused GEMM (gi+gh, 4 gate groups) + GRU gates + last-duplicate scatter
// C tile: TM=64 obs rows x TN=64 h cols; 256 threads, 4x4 micro-tile,
// 4 accumulator groups (r, z, inn, hn). K staged via LDS in KT=32 chunks.
// ---------------------------------------------------------------------------
#define TM 64
#define TN 64
#define KT 32

__global__ __launch_bounds__(256, 2) void gemm_gate_kernel(
    const float* __restrict__ A,
    const float* __restrict__ Wih,   // [1536][1024]
    const float* __restrict__ Whh,   // [1536][512]
    const float* __restrict__ bih,
    const float* __restrict__ bhh,
    const int* __restrict__ iobs,
    float* __restrict__ out, int nobs)
{
  __shared__ __align__(16) float As[KT][TM + 4];        // [k][row]
  __shared__ __align__(16) float Bs[3][KT][TN + 4];     // [gate][k][col]

  const int tid = threadIdx.x;
  const int tx = tid & 15;        // 16 col groups of 4
  const int ty = tid >> 4;        // 16 row groups of 4
  const int j0 = blockIdx.x * TM;
  const int k0 = blockIdx.y * TN;

  float accR[4][4] = {}, accZ[4][4] = {}, accI[4][4] = {}, accH[4][4] = {};

  // staging maps
  const int ar  = tid >> 3;        // 0..31 (row)
  const int ac4 = (tid & 7) * 4;   // 0..28 (col, float4)
  const int bk  = tid >> 2;        // 0..63 (W row = h col)
  const int bc4 = (tid & 3) * 4;   // 0..12 (k col, float4)

#define STAGE_TILE(Wptr, Kw, CLOC)                                            \
  {                                                                           \
    _Pragma("unroll")                                                         \
    for (int s = 0; s < 2; ++s) {                                             \
      int r = ar + s * 32;                                                    \
      int row = j0 + r;                                                       \
      int rowc = row < nobs ? row : nobs - 1;                                 \
      float4 v = *(const float4*)(A + (size_t)rowc * KTOT + cb + ac4);        \
      As[ac4 + 0][r] = v.x; As[ac4 + 1][r] = v.y;                             \
      As[ac4 + 2][r] = v.z; As[ac4 + 3][r] = v.w;                             \
    }                                                                         \
    _Pragma("unroll")                                                         \
    for (int g = 0; g < 3; ++g) {                                             \
      _Pragma("unroll")                                                       \
      for (int s = 0; s < 2; ++s) {                                           \
        int c = bc4 + s * 16;                                                 \
        float4 v = *(const float4*)(Wptr + (size_t)(k0 + bk + g * 512) * Kw + \
                                    (CLOC) + c);                              \
        Bs[g][c + 0][bk] = v.x; Bs[g][c + 1][bk] = v.y;                       \
        Bs[g][c + 2][bk] = v.z; Bs[g][c + 3][bk] = v.w;                       \
      }                                                                       \
    }                                                                         \
  }

#define KLOOP(ACC3)                                                           \
  {                                                                           \
    _Pragma("unroll")                                                         \
    for (int kk = 0; kk < KT; ++kk) {                                         \
      float4 a  = *(const float4*)&As[kk][ty * 4];                            \
      float4 b0 = *(const float4*)&Bs[0][kk][tx * 4];                         \
      float4 b1 = *(const float4*)&Bs[1][kk][tx * 4];                         \
      float4 b2 = *(const float4*)&Bs[2][kk][tx * 4];                         \
      float av[4]  = {a.x, a.y, a.z, a.w};                                    \
      float b0v[4] = {b0.x, b0.y, b0.z, b0.w};                                \
      float b1v[4] = {b1.x, b1.y, b1.z, b1.w};                                \
      float b2v[4] = {b2.x, b2.y, b2.z, b2.w};                                \
      _Pragma("unroll")                                                       \
      for (int mi = 0; mi < 4; ++mi) {                                        \
        _Pragma("unroll")                                                     \
        for (int ni = 0; ni < 4; ++ni) {                                      \
          accR[mi][ni] = fmaf(av[mi], b0v[ni], accR[mi][ni]);                 \
          accZ[mi][ni] = fmaf(av[mi], b1v[ni], accZ[mi][ni]);                 \
          ACC3[mi][ni] = fmaf(av[mi], b2v[ni], ACC3[mi][ni]);                 \
        }                                                                     \
      }                                                                       \
    }                                                                         \
  }

  // phase 1: K = 0..1023 over Wih -> accR, accZ, accI
  for (int cb = 0; cb < 1024; cb += KT) {
    STAGE_TILE(Wih, 1024, cb)
    __syncthreads();
    KLOOP(accI)
    __syncthreads();
  }
  // phase 2: K = 1024..1535 over Whh -> accR, accZ, accH
  for (int cb = 1024; cb < 1536; cb += KT) {
    STAGE_TILE(Whh, 512, cb - 1024)
    __syncthreads();
    KLOOP(accH)
    __syncthreads();
  }

  // epilogue: gates + scatter (last duplicate wins)
  const int kc = k0 + tx * 4;
  float4 bir4 = *(const float4*)(bih + kc);
  float4 biz4 = *(const float4*)(bih + 512 + kc);
  float4 bin4 = *(const float4*)(bih + 1024 + kc);
  float4 bhr4 = *(const float4*)(bhh + kc);
  float4 bhz4 = *(const float4*)(bhh + 512 + kc);
  float4 bhn4 = *(const float4*)(bhh + 1024 + kc);
  float bir[4] = {bir4.x, bir4.y, bir4.z, bir4.w};
  float biz[4] = {biz4.x, biz4.y, biz4.z, biz4.w};
  float bin[4] = {bin4.x, bin4.y, bin4.z, bin4.w};
  float bhr[4] = {bhr4.x, bhr4.y, bhr4.z, bhr4.w};
  float bhz[4] = {bhz4.x, bhz4.y, bhz4.z, bhz4.w};
  float bhn[4] = {bhn4.x, bhn4.y, bhn4.z, bhn4.w};

  #pragma unroll
  for (int mi = 0; mi < 4; ++mi) {
    int j = j0 + ty * 4 + mi;
    if (j >= nobs) continue;
    int i = iobs[j];
    bool last = (j == nobs - 1) || (iobs[j + 1] != i);
    if (!last) continue;   // numpy scatter: last occurrence wins
    float4 hp = *(const float4*)(A + (size_t)j * KTOT + 1024 + kc);
    float hv[4] = {hp.x, hp.y, hp.z, hp.w};
    float ov[4];
    #pragma unroll
    for (int ni = 0; ni < 4; ++ni) {
      float r = sigf(accR[mi][ni] + bir[ni] + bhr[ni]);
      float z = sigf(accZ[mi][ni] + biz[ni] + bhz[ni]);
      float n = tanhf(accI[mi][ni] + bin[ni] + r * (accH[mi][ni] + bhn[ni]));
      ov[ni] = (1.0f - z) * n + z * hv[ni];
    }
    float4 o = {ov[0], ov[1], ov[2], ov[3]};
    *(float4*)(out + (size_t)i * NHID + kc) = o;
  }
}

// ---------------------------------------------------------------------------
extern "C" void kernel_launch(void* const* d_in, const int* in_sizes, int n_in,
                              void* d_out, int out_size, void* d_ws, size_t ws_size,
                              hipStream_t stream) {
  const float* h     = (const float*)d_in[0];
  const float* p     = (const float*)d_in[1];
  const float* X     = (const float*)d_in[2];
  const float* Mm    = (const float*)d_in[3];
  const int*   iobs  = (const int*)d_in[4];
  const float* wprep = (const float*)d_in[5];
  const float* bprep = (const float*)d_in[6];
  const float* Wih   = (const float*)d_in[7];
  const float* Whh   = (const float*)d_in[8];
  const float* bih   = (const float*)d_in[9];
  const float* bhh   = (const float*)d_in[10];

  const int N    = in_sizes[0] / NHID;
  const int nobs = in_sizes[4];
  float* out = (float*)d_out;
  float* A   = (float*)d_ws;                 // [nobs][1536]
  float* loss = out + (size_t)N * NHID;

  // h_new = h (rows later overwritten by scatter); zero the loss slot
  hipMemcpyAsync(d_out, d_in[0], (size_t)N * NHID * sizeof(float),
                 hipMemcpyDeviceToDevice, stream);
  hipMemsetAsync((void*)loss, 0, sizeof(float), stream);

  int nb1 = (nobs * 64 + 255) / 256;
  prep_kernel<<<nb1, 256, 0, stream>>>(p, X, Mm, iobs, wprep, bprep, A, loss, nobs);
  int nb2 = (nobs * 128 + 255) / 256;
  gather_kernel<<<nb2, 256, 0, stream>>>(h, iobs, A, nobs);
  dim3 grid((nobs + TM - 1) / TM, NHID / TN);
  gemm_gate_kernel<<<grid, 256, 0, stream>>>(A, Wih, Whh, bih, bhh, iobs, out, nobs);
}

// Round 2
// 931.581 us; speedup vs baseline: 4.1892x; 4.1892x over previous
//
#include <hip/hip_runtime.h>
#include <math.h>

#define NHID 512
typedef unsigned short u16;
typedef __attribute__((ext_vector_type(8))) short short8;
typedef __attribute__((ext_vector_type(16))) float floatx16;

__device__ __forceinline__ unsigned f2b1(float f) {  // fp32 -> bf16 (RNE)
  unsigned u = __float_as_uint(f);
  return (u + 0x7FFFu + ((u >> 16) & 1u)) >> 16;
}
__device__ __forceinline__ unsigned pk2(float a, float b) {
  return f2b1(a) | (f2b1(b) << 16);
}
__device__ __forceinline__ float sigf(float x) { return 1.0f / (1.0f + expf(-x)); }

// ---------------------------------------------------------------------------
// weight transform: fp32 row-major W[3*512][Kw] -> bf16 fragment-major tiles
// unit u = (((cb*3+g)*nch + ch)*8 + g8)*64 + col  holds W[g*512+cb*64+col][ch*64+g8*8 .. +8]
// ---------------------------------------------------------------------------
__global__ void wtransform(const float* __restrict__ W, uint4* __restrict__ Wt,
                           int Kw, int nch) {
  int u = blockIdx.x * 256 + threadIdx.x;
  int total = 8 * 3 * nch * 512;
  if (u >= total) return;
  int col = u & 63;
  int g8 = (u >> 6) & 7;
  int ch = (u >> 9) % nch;
  int t3 = (u >> 9) / nch;
  int g = t3 % 3, cbb = t3 / 3;
  const float* src = W + (size_t)(g * 512 + cbb * 64 + col) * Kw + ch * 64 + g8 * 8;
  float4 f0 = *(const float4*)src;
  float4 f1 = *(const float4*)(src + 4);
  uint4 v = {pk2(f0.x, f0.y), pk2(f0.z, f0.w), pk2(f1.x, f1.y), pk2(f1.z, f1.w)};
  Wt[u] = v;
}

// ---------------------------------------------------------------------------
// prep: loss partials, last-duplicate compaction, gru_in->A_in (bf16),
// h gather->A_h (bf16). One wave (64 lanes = 64 d's) per obs row.
// ---------------------------------------------------------------------------
__global__ void prep_kernel(const float* __restrict__ p,
                            const float* __restrict__ X,
                            const float* __restrict__ Mm,
                            const int* __restrict__ iobs,
                            const float* __restrict__ wprep,
                            const float* __restrict__ bprep,
                            const float* __restrict__ h,
                            u16* __restrict__ A_in, u16* __restrict__ A_h,
                            int* __restrict__ map_i, int* __restrict__ counter,
                            float* __restrict__ partials, int nobs)
{
  __shared__ float sw[4096];
  __shared__ float sb[1024];
  __shared__ int s_cnt[4];
  __shared__ float s_loss[4];
  for (int t = threadIdx.x; t < 4096; t += 256) sw[t] = wprep[t];
  for (int t = threadIdx.x; t < 1024; t += 256) sb[t] = bprep[t];

  const int tid = threadIdx.x;
  const int wave = tid >> 6;
  const int d = tid & 63;
  const int j = blockIdx.x * 4 + wave;
  const bool act = j < nobs;

  int i = 0; bool lastf = false;
  float x = 0.f, mean = 0.f, var = 1.f, m = 0.f, err = 0.f, lossp = 0.f;
  if (act) {
    i = iobs[j];
    lastf = (j == nobs - 1) || (iobs[j + 1] != i);
    mean = p[(size_t)i * 128 + d];
    var  = fabsf(p[(size_t)i * 128 + 64 + d]) + 1e-6f;
    x = X[(size_t)j * 64 + d];
    m = Mm[(size_t)j * 64 + d];
    err = (x - mean) * rsqrtf(var);
    lossp = 0.5f * (err * err + logf(var)) * m;
  }
  __syncthreads();   // sw/sb ready

  #pragma unroll
  for (int off = 32; off > 0; off >>= 1) lossp += __shfl_down(lossp, off, 64);
  if (d == 0) { s_loss[wave] = lossp; s_cnt[wave] = (act && lastf) ? 1 : 0; }
  __syncthreads();
  if (tid == 0) {
    int c0 = s_cnt[0], c1 = s_cnt[1], c2 = s_cnt[2], c3 = s_cnt[3];
    int tot = c0 + c1 + c2 + c3;
    int base = tot ? atomicAdd(counter, tot) : 0;
    s_cnt[0] = base; s_cnt[1] = base + c0;
    s_cnt[2] = base + c0 + c1; s_cnt[3] = base + c0 + c1 + c2;
    partials[blockIdx.x] = s_loss[0] + s_loss[1] + s_loss[2] + s_loss[3];
  }
  __syncthreads();

  if (act && lastf) {
    const int slot = s_cnt[wave];
    if (d == 0) map_i[slot] = i;
    // gru_in features -> bf16
    const float* w = sw + d * 64;   // [4][16]
    const float* b = sb + d * 16;
    float gi[16];
    #pragma unroll
    for (int ph = 0; ph < 16; ++ph) {
      float v = x * w[ph] + mean * w[16 + ph] + var * w[32 + ph] + err * w[48 + ph] + b[ph];
      gi[ph] = fmaxf(v, 0.0f) * m;
    }
    uint4* dst = (uint4*)(A_in + (size_t)slot * 1024 + d * 16);
    uint4 v0 = {pk2(gi[0], gi[1]), pk2(gi[2], gi[3]), pk2(gi[4], gi[5]), pk2(gi[6], gi[7])};
    uint4 v1 = {pk2(gi[8], gi[9]), pk2(gi[10], gi[11]), pk2(gi[12], gi[13]), pk2(gi[14], gi[15])};
    dst[0] = v0; dst[1] = v1;
    // h gather -> bf16
    const float4* hp = (const float4*)(h + (size_t)i * NHID + d * 8);
    float4 a = hp[0], bb = hp[1];
    uint4 hv = {pk2(a.x, a.y), pk2(a.z, a.w), pk2(bb.x, bb.y), pk2(bb.z, bb.w)};
    *(uint4*)(A_h + (size_t)slot * 512 + d * 8) = hv;
  }
}

// ---------------------------------------------------------------------------
__global__ void loss_sum(const float* __restrict__ partials, int n,
                         float* __restrict__ loss) {
  float s = 0.f;
  for (int t = threadIdx.x; t < n; t += 256) s += partials[t];
  #pragma unroll
  for (int off = 32; off > 0; off >>= 1) s += __shfl_down(s, off, 64);
  __shared__ float sw4[4];
  if ((threadIdx.x & 63) == 0) sw4[threadIdx.x >> 6] = s;
  __syncthreads();
  if (threadIdx.x == 0) loss[0] = sw4[0] + sw4[1] + sw4[2] + sw4[3];
}

// ---------------------------------------------------------------------------
// MFMA GEMM: 64 rows x (64 h-cols x 3 gates), 4 waves 2x2, wave tile 32x32
// per acc group (R,Z,I,H). Fragment-major LDS (conflict-free b128).
// ---------------------------------------------------------------------------
__global__ __launch_bounds__(256, 4) void gemm_mfma(
    const u16* __restrict__ A_in, const u16* __restrict__ A_h,
    const uint4* __restrict__ Wt_ih, const uint4* __restrict__ Wt_hh,
    const int* __restrict__ map_i, const int* __restrict__ counter,
    const float* __restrict__ h,
    const float* __restrict__ bih, const float* __restrict__ bhh,
    float* __restrict__ out)
{
  const int ndist = *counter;
  const int j0 = blockIdx.y * 64;
  if (j0 >= ndist) return;
  const int cb = blockIdx.x;        // 0..7 (h-col block of 64)
  const int tid = threadIdx.x;
  const int lane = tid & 63;
  const int wave = tid >> 6;
  const int wrow = wave >> 1, wcol = wave & 1;
  const int l31 = lane & 31, kh = lane >> 5;

  __shared__ uint4 sA[8 * 64];        // 8 KB  [g8][row]
  __shared__ uint4 sB[3 * 8 * 64];    // 24 KB [gate][g8][col]

  floatx16 accR = {}, accZ = {}, accI = {}, accH = {};

#define STAGE(Asrc, Ks, Wt, NCH, ch)                                         \
  {                                                                          \
    _Pragma("unroll") for (int pp = 0; pp < 2; ++pp) {                       \
      int g8 = (tid >> 6) + pp * 4;                                          \
      int row = tid & 63;                                                    \
      int gr = j0 + row; if (gr >= ndist) gr = ndist - 1;                    \
      sA[g8 * 64 + row] =                                                    \
          *(const uint4*)(Asrc + (size_t)gr * Ks + ch * 64 + g8 * 8);        \
    }                                                                        \
    _Pragma("unroll") for (int pp = 0; pp < 6; ++pp) {                       \
      int idx = pp * 256 + tid;                                              \
      int g = idx >> 9, rem = idx & 511;                                     \
      sB[idx] = Wt[(size_t)((cb * 3 + g) * NCH + ch) * 512 + rem];           \
    }                                                                        \
  }

#define KSTEPS(ACC3)                                                         \
  _Pragma("unroll") for (int s = 0; s < 4; ++s) {                            \
    int u = (s * 2 + kh) * 64;                                               \
    uint4 av = sA[u + l31 + 32 * wrow];                                      \
    uint4 b0 = sB[0 * 512 + u + l31 + 32 * wcol];                            \
    uint4 b1 = sB[1 * 512 + u + l31 + 32 * wcol];                            \
    uint4 b2 = sB[2 * 512 + u + l31 + 32 * wcol];                            \
    short8 aF = __builtin_bit_cast(short8, av);                              \
    short8 f0 = __builtin_bit_cast(short8, b0);                              \
    short8 f1 = __builtin_bit_cast(short8, b1);                              \
    short8 f2 = __builtin_bit_cast(short8, b2);                              \
    accR = __builtin_amdgcn_mfma_f32_32x32x16_bf16(aF, f0, accR, 0, 0, 0);   \
    accZ = __builtin_amdgcn_mfma_f32_32x32x16_bf16(aF, f1, accZ, 0, 0, 0);   \
    ACC3 = __builtin_amdgcn_mfma_f32_32x32x16_bf16(aF, f2, ACC3, 0, 0, 0);   \
  }

  // phase 1: gru_in @ Wih^T  (K = 1024, 16 chunks of 64)
  for (int ch = 0; ch < 16; ++ch) {
    STAGE(A_in, 1024, Wt_ih, 16, ch)
    __syncthreads();
    KSTEPS(accI)
    __syncthreads();
  }
  // phase 2: h_prev @ Whh^T  (K = 512, 8 chunks of 64)
  for (int ch = 0; ch < 8; ++ch) {
    STAGE(A_h, 512, Wt_hh, 8, ch)
    __syncthreads();
    KSTEPS(accH)
    __syncthreads();
  }

  // epilogue: gates + scatter (compacted rows are unique i's)
  const int col = cb * 64 + 32 * wcol + l31;
  const float biR = bih[col], biZ = bih[512 + col], biN = bih[1024 + col];
  const float bhR = bhh[col], bhZ = bhh[512 + col], bhN = bhh[1024 + col];
  #pragma unroll
  for (int r = 0; r < 16; ++r) {
    int rowl = (r & 3) + 8 * (r >> 2) + 4 * kh + 32 * wrow;
    int jg = j0 + rowl;
    if (jg >= ndist) continue;
    int i = map_i[jg];
    float hv = h[(size_t)i * NHID + col];
    float rr = sigf(accR[r] + biR + bhR);
    float zz = sigf(accZ[r] + biZ + bhZ);
    float nn = tanhf(accI[r] + biN + rr * (accH[r] + bhN));
    out[(size_t)i * NHID + col] = (1.0f - zz) * nn + zz * hv;
  }
#undef STAGE
#undef KSTEPS
}

// ---------------------------------------------------------------------------
extern "C" void kernel_launch(void* const* d_in, const int* in_sizes, int n_in,
                              void* d_out, int out_size, void* d_ws, size_t ws_size,
                              hipStream_t stream) {
  const float* h     = (const float*)d_in[0];
  const float* p     = (const float*)d_in[1];
  const float* X     = (const float*)d_in[2];
  const float* Mm    = (const float*)d_in[3];
  const int*   iobs  = (const int*)d_in[4];
  const float* wprep = (const float*)d_in[5];
  const float* bprep = (const float*)d_in[6];
  const float* Wih   = (const float*)d_in[7];
  const float* Whh   = (const float*)d_in[8];
  const float* bih   = (const float*)d_in[9];
  const float* bhh   = (const float*)d_in[10];

  const int N    = in_sizes[0] / NHID;
  const int nobs = in_sizes[4];
  float* out = (float*)d_out;
  float* loss = out + (size_t)N * NHID;

  // workspace layout (bytes)
  char* ws = (char*)d_ws;
  int*   counter  = (int*)ws;                                   // 4 B
  int*   map_i    = (int*)(ws + 1024);                          // nobs * 4
  float* partials = (float*)(ws + (256 << 10));                 // nblocks * 4
  u16*   A_in     = (u16*)(ws + (1 << 20));                     // nobs*1024*2
  u16*   A_h      = (u16*)((char*)A_in + (size_t)nobs * 2048);  // nobs*512*2
  uint4* Wt_ih    = (uint4*)((char*)A_h + (size_t)nobs * 1024); // 3 MB
  uint4* Wt_hh    = (uint4*)((char*)Wt_ih + (size_t)3145728);   // 1.5 MB

  hipMemcpyAsync(d_out, d_in[0], (size_t)N * NHID * sizeof(float),
                 hipMemcpyDeviceToDevice, stream);
  hipMemsetAsync(counter, 0, 4, stream);

  wtransform<<<768, 256, 0, stream>>>(Wih, Wt_ih, 1024, 16);
  wtransform<<<384, 256, 0, stream>>>(Whh, Wt_hh, 512, 8);

  int nblocks = (nobs + 3) / 4;
  prep_kernel<<<nblocks, 256, 0, stream>>>(p, X, Mm, iobs, wprep, bprep, h,
                                           A_in, A_h, map_i, counter, partials, nobs);
  loss_sum<<<1, 256, 0, stream>>>(partials, nblocks, loss);

  dim3 grid(8, (nobs + 63) / 64);
  gemm_mfma<<<grid, 256, 0, stream>>>(A_in, A_h, Wt_ih, Wt_hh, map_i, counter,
                                      h, bih, bhh, out);
}